// Round 2
// baseline (829.347 us; speedup 1.0000x reference)
//
#include <hip/hip_runtime.h>
#include <math.h>

#define NLAT 721
#define NLON 1440
#define KLEV 24
#define S_LVL (NLAT * NLON)            /* 1038240 */
#define WBLK 6                         /* ceil(1440/256) */
#define NBLK (WBLK * NLAT)             /* 4326 */

#define OFF_DT  (KLEV * S_LVL * 2)     /* 49835520 */
#define OFF_DQ  (OFF_DT + KLEV * S_LVL)/* 74753280 */
#define OFF_DPS (OFF_DQ + KLEV * S_LVL)/* 99671040 */

// ---- hybrid-coordinate interface b (match np.linspace(1.0,0.04,25).astype(f32)) ----
__device__ __forceinline__ float BIF(int i) {
  if (i >= KLEV) return 0.04f;
  return (float)(1.0 + ((0.04 - 1.0) / 24.0) * (double)i);
}

// ---- latitude tables (match np.linspace(0,pi,721) colatitude, f32 cast) ----
__device__ __forceinline__ float latf(int i) {
  double colat = (i == NLAT - 1) ? M_PI : (M_PI / 720.0) * (double)i;
  return (float)(M_PI / 2.0 - colat);
}
__device__ __forceinline__ float coslatf(int i) {
  return fmaxf(cosf(latf(i)), 1e-3f);
}

// _dphi core: -(one-sided/central diff)/DTHETA ; h uniform per block -> no divergence
__device__ __forceinline__ float dphi3(float xn, float xc, float xs, int h, float invdth) {
  float d = (h == 0) ? (xs - xc) : (h == NLAT - 1) ? (xc - xn) : (xs - xn) * 0.5f;
  return -d * invdth;
}

// bijective XCD swizzle: each of 8 XCDs gets a contiguous latitude band
__device__ __forceinline__ void remap(int lb, int& h, int& w) {
  const int q = NBLK >> 3, r = NBLK & 7;
  int xcd = lb & 7, idx = lb >> 3;
  int wg = (xcd < r ? xcd * (q + 1) : r * (q + 1) + (xcd - r) * q) + idx;
  h = wg / WBLK;
  int bx = wg - h * WBLK;
  w = bx * 256 + (int)threadIdx.x;
}

__global__ __launch_bounds__(256) void kern_dpsdt(const float* __restrict__ uv,
                                                  const float* __restrict__ ps,
                                                  float* __restrict__ out) {
  int h, w;
  remap((int)blockIdx.x, h, w);
  if (w >= NLON) return;

  const int hN = (h > 0) ? h - 1 : 0;
  const int hS = (h < NLAT - 1) ? h + 1 : NLAT - 1;
  const int wE = (w == NLON - 1) ? 0 : w + 1;
  const int wW = (w == 0) ? NLON - 1 : w - 1;
  const int iC = h * NLON + w, iE = h * NLON + wE, iW = h * NLON + wW;
  const int iN = hN * NLON + w, iS = hS * NLON + w;

  const float cosC = coslatf(h), cosN = coslatf(hN), cosS = coslatf(hS);
  const float DLAM = (float)(2.0 * M_PI / 1440.0);
  const float DTHETA = (float)(M_PI / 720.0);
  const float inv2dlam = 1.0f / (2.0f * DLAM);
  const float invdth = 1.0f / DTHETA;
  const float invRcos = 1.0f / (6371000.0f * cosC);
  const float invR = 1.0f / 6371000.0f;

  const float psC = ps[iC], psE = ps[iE], psW = ps[iW], psN = ps[iN], psS = ps[iS];
  const float gpsx = (psE - psW) * inv2dlam * invRcos;
  const float gpsy = dphi3(psN, psC, psS, h, invdth) * invR;

  float acc = 0.0f;
  float bifc = 1.0f; /* BIF(0) */
#pragma unroll 4
  for (int k = 0; k < KLEV; ++k) {
    const float* lvl = uv + (size_t)k * (size_t)(S_LVL * 2);
    const float2 c = *(const float2*)(lvl + 2 * iC);
    const float eu = lvl[2 * iE], wu = lvl[2 * iW];
    const float nv = lvl[2 * iN + 1], sv = lvl[2 * iS + 1];
    const float bifn = BIF(k + 1);
    const float db = bifn - bifc;
    bifc = bifn;
    float dlam_u = (eu - wu) * inv2dlam;
    float dphi_vc = dphi3(nv * cosN, c.y * cosC, sv * cosS, h, invdth);
    float divg = (dlam_u + dphi_vc) * invRcos;
    float vgps = c.x * gpsx + c.y * gpsy;
    float dp = db * psC;
    acc += dp * divg + db * vgps;
  }
  out[OFF_DPS + iC] = -acc;
}

__global__ __launch_bounds__(256) void kern_tend(const float* __restrict__ uv,
                                                 const float* __restrict__ Tf,
                                                 const float* __restrict__ qf,
                                                 const float* __restrict__ ps,
                                                 float* __restrict__ out) {
  int h, w;
  remap((int)blockIdx.x, h, w);
  if (w >= NLON) return;

  const int hN = (h > 0) ? h - 1 : 0;
  const int hS = (h < NLAT - 1) ? h + 1 : NLAT - 1;
  const int wE = (w == NLON - 1) ? 0 : w + 1;
  const int wW = (w == 0) ? NLON - 1 : w - 1;
  const int iC = h * NLON + w, iE = h * NLON + wE, iW = h * NLON + wW;
  const int iN = hN * NLON + w, iS = hS * NLON + w;

  const float cosC = coslatf(h), cosN = coslatf(hN), cosS = coslatf(hS);
  const float DLAM = (float)(2.0 * M_PI / 1440.0);
  const float DTHETA = (float)(M_PI / 720.0);
  const float inv2dlam = 1.0f / (2.0f * DLAM);
  const float invdth = 1.0f / DTHETA;
  const float invRcos = 1.0f / (6371000.0f * cosC);
  const float invR = 1.0f / 6371000.0f;
  const float KAPPA = (float)(287.0 / 1004.0);
  const float TWO_OMEGA = (float)(2.0 * 7.292e-05);
  const float fcor = TWO_OMEGA * sinf(latf(h));

  const float psC = ps[iC], psE = ps[iE], psW = ps[iW], psN = ps[iN], psS = ps[iS];
  const float gpsx = (psE - psW) * inv2dlam * invRcos;
  const float gpsy = dphi3(psN, psC, psS, h, invdth) * invR;

  const float dpsdt = out[OFF_DPS + iC];

  const float2* __restrict__ uv2 = (const float2*)uv;
  float2* duv2 = (float2*)out; /* duv at offset 0 */

  // center vertical pipeline: levels m-1, m, m+1
  float u_m1 = 0.f, v_m1 = 0.f, T_m1 = 0.f, q_m1 = 0.f;
  float2 c0 = uv2[iC];
  float u_0 = c0.x, v_0 = c0.y;
  float T_0 = Tf[iC], q_0 = qf[iC];
  float2 c1 = uv2[S_LVL + iC];
  float u_p1 = c1.x, v_p1 = c1.y;
  float T_p1 = Tf[S_LVL + iC], q_p1 = qf[S_LVL + iC];

  // hydrostatic phi running accumulators for center + 4 neighbor columns
  float phiC = 0.f, phiE = 0.f, phiW = 0.f, phiN = 0.f, phiS = 0.f;
  float TEp = 0.f, TWp = 0.f, TNp = 0.f, TSp = 0.f; // neighbor T at level m-1
  float Chalf = 0.f;                                 // C_half[m]

  for (int m = 0; m < KLEV; ++m) {
    const int base = m * S_LVL;
    // per-level coordinate constants (f64 linspace replay, f32 arithmetic after)
    const float bifc = BIF(m), bifn = BIF(m + 1);
    const float db = bifn - bifc;
    const float bmC = 0.5f * (bifn + bifc);                       // bm[m]
    const float bmP = (m > 0) ? 0.5f * (bifc + BIF(m - 1)) : 0.f; // bm[m-1]
    const float bmN = (m < KLEV - 1) ? 0.5f * (BIF(m + 2) + bifn) : 0.f; // bm[m+1]

    // neighbor loads at level m
    float2 e = uv2[base + iE];
    float2 ww = uv2[base + iW];
    float2 n = uv2[base + iN];
    float2 s = uv2[base + iS];
    const float TE = Tf[base + iE], TW = Tf[base + iW], TN = Tf[base + iN], TS = Tf[base + iS];
    const float qE = qf[base + iE], qW = qf[base + iW], qN = qf[base + iN], qS = qf[base + iS];

    // phi_m = phi_{m-1} + R*T_{m-1}*log(p_{m-1}/p_m); ps cancels in the ratio
    if (m > 0) {
      const float lr = logf(bmP / bmC); // column-independent to ~1e-7 abs
      phiC += (287.0f * T_m1) * lr;
      phiE += (287.0f * TEp) * lr;
      phiW += (287.0f * TWp) * lr;
      phiN += (287.0f * TNp) * lr;
      phiS += (287.0f * TSp) * lr;
    }

    // ke + phi at 5 points -> grad
    const float kC = 0.5f * (u_0 * u_0 + v_0 * v_0) + phiC;
    const float kE = 0.5f * (e.x * e.x + e.y * e.y) + phiE;
    const float kW = 0.5f * (ww.x * ww.x + ww.y * ww.y) + phiW;
    const float kN = 0.5f * (n.x * n.x + n.y * n.y) + phiN;
    const float kS = 0.5f * (s.x * s.x + s.y * s.y) + phiS;
    const float gkx = (kE - kW) * inv2dlam * invRcos;
    const float gky = dphi3(kN, kC, kS, h, invdth) * invR;

    const float zeta = ((e.y - ww.y) * inv2dlam -
                        dphi3(n.x * cosN, u_0 * cosC, s.x * cosS, h, invdth)) * invRcos;
    const float divg = ((e.x - ww.x) * inv2dlam +
                        dphi3(n.y * cosN, v_0 * cosC, s.y * cosS, h, invdth)) * invRcos;
    const float vgps = u_0 * gpsx + v_0 * gpsy;

    const float dp = db * psC;
    const float term = db * dpsdt + dp * divg + db * vgps;
    const float Cnext = Chalf - term;           // C_half[m+1]
    const float Cmid = 0.5f * (Chalf + Cnext);
    const float p_cur = bmC * psC;
    const float omega = bmC * (dpsdt + vgps) + Cmid;

    const float gTx = (TE - TW) * inv2dlam * invRcos;
    const float gTy = dphi3(TN, T_0, TS, h, invdth) * invR;
    const float gqx = (qE - qW) * inv2dlam * invRcos;
    const float gqy = dphi3(qN, q_0, qS, h, invdth) * invR;

    // ddp: one-sided top/bottom, central interior (shared denominator)
    float num_u, num_v, num_T, num_q, dden;
    if (m == 0) {
      dden = bmN * psC - p_cur;
      num_u = u_p1 - u_0; num_v = v_p1 - v_0; num_T = T_p1 - T_0; num_q = q_p1 - q_0;
    } else if (m == KLEV - 1) {
      dden = p_cur - bmP * psC;
      num_u = u_0 - u_m1; num_v = v_0 - v_m1; num_T = T_0 - T_m1; num_q = q_0 - q_m1;
    } else {
      dden = bmN * psC - bmP * psC;
      num_u = u_p1 - u_m1; num_v = v_p1 - v_m1; num_T = T_p1 - T_m1; num_q = q_p1 - q_m1;
    }
    const float invdden = 1.0f / dden;
    const float ddpu = num_u * invdden;
    const float ddpv = num_v * invdden;
    const float ddpT = num_T * invdden;
    const float ddpq = num_q * invdden;

    const float invp = 1.0f / p_cur;
    const float pgf = (287.0f * T_0) * bmC * invp; // R*T*bm/p
    const float av = zeta + fcor;

    const float du = ((av * v_0 - gkx) - pgf * gpsx) - Cmid * ddpu;
    const float dv = ((-av * u_0 - gky) - pgf * gpsy) - Cmid * ddpv;
    const float dTt = (-(u_0 * gTx + v_0 * gTy) - Cmid * ddpT) + ((KAPPA * T_0) * omega) * invp;
    const float dqt = -(u_0 * gqx + v_0 * gqy) - Cmid * ddpq;

    duv2[base + iC] = make_float2(du, dv);
    out[OFF_DT + base + iC] = dTt;
    out[OFF_DQ + base + iC] = dqt;

    // roll vertical state
    Chalf = Cnext;
    TEp = TE; TWp = TW; TNp = TN; TSp = TS;
    u_m1 = u_0; v_m1 = v_0; T_m1 = T_0; q_m1 = q_0;
    u_0 = u_p1; v_0 = v_p1; T_0 = T_p1; q_0 = q_p1;
    if (m + 2 < KLEV) {
      const int bn = (m + 2) * S_LVL;
      float2 cn = uv2[bn + iC];
      u_p1 = cn.x; v_p1 = cn.y;
      T_p1 = Tf[bn + iC];
      q_p1 = qf[bn + iC];
    }
  }
}

extern "C" void kernel_launch(void* const* d_in, const int* in_sizes, int n_in,
                              void* d_out, int out_size, void* d_ws, size_t ws_size,
                              hipStream_t stream) {
  const float* uv = (const float*)d_in[0];
  const float* T  = (const float*)d_in[1];
  const float* q  = (const float*)d_in[2];
  const float* ps = (const float*)d_in[3];
  float* out = (float*)d_out;
  (void)in_sizes; (void)n_in; (void)out_size; (void)d_ws; (void)ws_size;

  dim3 grid(NBLK), block(256);
  hipLaunchKernelGGL(kern_dpsdt, grid, block, 0, stream, uv, ps, out);
  hipLaunchKernelGGL(kern_tend, grid, block, 0, stream, uv, T, q, ps, out);
}

// Round 3
// 812.008 us; speedup vs baseline: 1.0214x; 1.0214x over previous
//
#include <hip/hip_runtime.h>
#include <math.h>

#define NLAT 721
#define NLON 1440
#define KLEV 24
#define S_LVL (NLAT * NLON)            /* 1038240 */
#define WBLK 6                         /* ceil(1440/256) */
#define NBLK (WBLK * NLAT)             /* 4326 */

#define OFF_DT  (KLEV * S_LVL * 2)     /* 49835520 */
#define OFF_DQ  (OFF_DT + KLEV * S_LVL)/* 74753280 */
#define OFF_DPS (OFF_DQ + KLEV * S_LVL)/* 99671040 */

typedef float f32x2 __attribute__((ext_vector_type(2)));

// per-level constants computed on HOST, passed by value -> kernarg (SGPR loads, no VALU)
struct Tabs {
  float rlr[KLEV];    // 287 * log(bm[m-1]/bm[m]) ; [0] unused
  float bm[KLEV];     // mid-level b
  float db[KLEV];     // interface delta b
  float invbm[KLEV];  // 1/bm
  float dc[KLEV];     // 1/(bm-difference) for ddp denominators
};

// latitude replay of np.linspace(0,pi,721) colatitude, f32 cast (prologue only)
__device__ __forceinline__ float latf(int i) {
  double colat = (i == NLAT - 1) ? M_PI : (M_PI / 720.0) * (double)i;
  return (float)(M_PI / 2.0 - colat);
}
__device__ __forceinline__ float coslatf(int i) { return fmaxf(cosf(latf(i)), 1e-3f); }

// _dphi core: -(one-sided/central diff)/DTHETA ; h uniform per block -> no divergence
__device__ __forceinline__ float dphi3(float xn, float xc, float xs, int h, float invdth) {
  float d = (h == 0) ? (xs - xc) : (h == NLAT - 1) ? (xc - xn) : (xs - xn) * 0.5f;
  return -d * invdth;
}

// bijective XCD swizzle: each of 8 XCDs gets a contiguous latitude band
__device__ __forceinline__ void remap(int lb, int& h, int& w) {
  const int q = NBLK >> 3, r = NBLK & 7;
  int xcd = lb & 7, idx = lb >> 3;
  int wg = (xcd < r ? xcd * (q + 1) : r * (q + 1) + (xcd - r) * q) + idx;
  h = wg / WBLK;
  int bx = wg - h * WBLK;
  w = bx * 256 + (int)threadIdx.x;
}

__global__ __launch_bounds__(256) void kern_fused(
    const float* __restrict__ uv, const float* __restrict__ Tf,
    const float* __restrict__ qf, const float* __restrict__ ps,
    float* __restrict__ out, Tabs tb)
{
  int h, w;
  remap((int)blockIdx.x, h, w);
  if (w >= NLON) return;

  const int hN = (h > 0) ? h - 1 : 0;
  const int hS = (h < NLAT - 1) ? h + 1 : NLAT - 1;
  const int wE = (w == NLON - 1) ? 0 : w + 1;
  const int wW = (w == 0) ? NLON - 1 : w - 1;
  const int iC = h * NLON + w, iE = h * NLON + wE, iW = h * NLON + wW;
  const int iN = hN * NLON + w, iS = hS * NLON + w;

  const float cosC = coslatf(h), cosN = coslatf(hN), cosS = coslatf(hS);
  const float DLAM = (float)(2.0 * M_PI / 1440.0);
  const float DTHETA = (float)(M_PI / 720.0);
  const float inv2dlam = 1.0f / (2.0f * DLAM);
  const float invdth = 1.0f / DTHETA;
  const float invRcos = 1.0f / (6371000.0f * cosC);
  const float invR = 1.0f / 6371000.0f;
  const float gxc = inv2dlam * invRcos;          // zonal-diff combined scale
  const float KAPPA = (float)(287.0 / 1004.0);
  const float TWO_OMEGA = (float)(2.0 * 7.292e-05);
  const float fcor = TWO_OMEGA * sinf(latf(h));

  const float psC = ps[iC], psE = ps[iE], psW = ps[iW], psN = ps[iN], psS = ps[iS];
  const float invps = 1.0f / psC;                // the only divide in the kernel
  const float gpsx = (psE - psW) * gxc;
  const float gpsy = dphi3(psN, psC, psS, h, invdth) * invR;

  // ---------------- pass 1: dpsdt (full-column sum) ----------------
  float acc = 0.0f;
#pragma unroll 6
  for (int k = 0; k < KLEV; ++k) {
    const float* lvl = uv + (size_t)(2 * k) * (size_t)S_LVL;
    const f32x2 c = *(const f32x2*)(lvl + 2 * iC);
    const float eu = lvl[2 * iE], wu = lvl[2 * iW];
    const float nv = lvl[2 * iN + 1], sv = lvl[2 * iS + 1];
    float divg = (eu - wu) * gxc +
                 dphi3(nv * cosN, c.y * cosC, sv * cosS, h, invdth) * invRcos;
    float vgps = c.x * gpsx + c.y * gpsy;
    acc += tb.db[k] * (psC * divg + vgps);       // dp*divg + db*vgps, db factored
  }
  const float dpsdt = -acc;
  __builtin_nontemporal_store(dpsdt, out + OFF_DPS + iC);

  // ---------------- pass 2: per-level tendencies ----------------
  const f32x2* __restrict__ uv2 = (const f32x2*)uv;
  f32x2* duv2 = (f32x2*)out;

  // center vertical pipeline: levels m-1, m, m+1
  float u_m1 = 0.f, v_m1 = 0.f, T_m1 = 0.f, q_m1 = 0.f;
  f32x2 c0 = uv2[iC];
  float u_0 = c0.x, v_0 = c0.y;
  float T_0 = Tf[iC], q_0 = qf[iC];
  f32x2 c1 = uv2[S_LVL + iC];
  float u_p1 = c1.x, v_p1 = c1.y;
  float T_p1 = Tf[S_LVL + iC], q_p1 = qf[S_LVL + iC];

  // hydrostatic phi running accumulators for center + 4 neighbor columns
  float phiC = 0.f, phiE = 0.f, phiW = 0.f, phiN = 0.f, phiS = 0.f;
  float TEp = 0.f, TWp = 0.f, TNp = 0.f, TSp = 0.f;
  float Chalf = 0.f;                              // C_half[m]

  for (int m = 0; m < KLEV; ++m) {
    const int base = m * S_LVL;
    const float bmC = tb.bm[m];
    const float db = tb.db[m];

    // neighbor loads at level m
    f32x2 e = uv2[base + iE];
    f32x2 ww = uv2[base + iW];
    f32x2 n = uv2[base + iN];
    f32x2 s = uv2[base + iS];
    const float TE = Tf[base + iE], TW = Tf[base + iW], TN = Tf[base + iN], TS = Tf[base + iS];
    const float qE = qf[base + iE], qW = qf[base + iW], qN = qf[base + iN], qS = qf[base + iS];

    // phi_m = phi_{m-1} + (R*lr)*T_{m-1}; lr column-independent (ps cancels)
    if (m > 0) {
      const float rlr = tb.rlr[m];
      phiC += T_m1 * rlr;
      phiE += TEp * rlr;
      phiW += TWp * rlr;
      phiN += TNp * rlr;
      phiS += TSp * rlr;
    }

    // ke + phi at 5 points -> grad
    const float kC = 0.5f * (u_0 * u_0 + v_0 * v_0) + phiC;
    const float kE = 0.5f * (e.x * e.x + e.y * e.y) + phiE;
    const float kW = 0.5f * (ww.x * ww.x + ww.y * ww.y) + phiW;
    const float kN = 0.5f * (n.x * n.x + n.y * n.y) + phiN;
    const float kS = 0.5f * (s.x * s.x + s.y * s.y) + phiS;
    const float gkx = (kE - kW) * gxc;
    const float gky = dphi3(kN, kC, kS, h, invdth) * invR;

    const float zeta = (e.y - ww.y) * gxc -
                       dphi3(n.x * cosN, u_0 * cosC, s.x * cosS, h, invdth) * invRcos;
    const float divg = (e.x - ww.x) * gxc +
                       dphi3(n.y * cosN, v_0 * cosC, s.y * cosS, h, invdth) * invRcos;
    const float vgps = u_0 * gpsx + v_0 * gpsy;

    const float term = db * (dpsdt + psC * divg + vgps);
    const float Cnext = Chalf - term;             // C_half[m+1]
    const float Cmid = 0.5f * (Chalf + Cnext);
    const float omega = bmC * (dpsdt + vgps) + Cmid;
    const float invp = tb.invbm[m] * invps;       // 1/p_cur, no divide

    const float gTx = (TE - TW) * gxc;
    const float gTy = dphi3(TN, T_0, TS, h, invdth) * invR;
    const float gqx = (qE - qW) * gxc;
    const float gqy = dphi3(qN, q_0, qS, h, invdth) * invR;

    // ddp: one-sided top/bottom, central interior; denominator via host table
    float num_u, num_v, num_T, num_q;
    if (m == 0) {
      num_u = u_p1 - u_0; num_v = v_p1 - v_0; num_T = T_p1 - T_0; num_q = q_p1 - q_0;
    } else if (m == KLEV - 1) {
      num_u = u_0 - u_m1; num_v = v_0 - v_m1; num_T = T_0 - T_m1; num_q = q_0 - q_m1;
    } else {
      num_u = u_p1 - u_m1; num_v = v_p1 - v_m1; num_T = T_p1 - T_m1; num_q = q_p1 - q_m1;
    }
    const float invdden = tb.dc[m] * invps;       // 1/(p-diff), no divide
    const float CmidD = Cmid * invdden;           // Cmid * ddp = CmidD * num

    const float pgf = (287.0f * T_0) * invps;     // R*T*bm/p with bm/bm folded
    const float av = zeta + fcor;

    const float du = ((av * v_0 - gkx) - pgf * gpsx) - CmidD * num_u;
    const float dv = ((-av * u_0 - gky) - pgf * gpsy) - CmidD * num_v;
    const float dTt = (-(u_0 * gTx + v_0 * gTy) - CmidD * num_T)
                      + ((KAPPA * T_0) * omega) * invp;
    const float dqt = -(u_0 * gqx + v_0 * gqy) - CmidD * num_q;

    f32x2 r; r.x = du; r.y = dv;
    __builtin_nontemporal_store(r, duv2 + base + iC);
    __builtin_nontemporal_store(dTt, out + OFF_DT + base + iC);
    __builtin_nontemporal_store(dqt, out + OFF_DQ + base + iC);

    // roll vertical state
    Chalf = Cnext;
    TEp = TE; TWp = TW; TNp = TN; TSp = TS;
    u_m1 = u_0; v_m1 = v_0; T_m1 = T_0; q_m1 = q_0;
    u_0 = u_p1; v_0 = v_p1; T_0 = T_p1; q_0 = q_p1;
    if (m + 2 < KLEV) {
      const int bn = (m + 2) * S_LVL;
      f32x2 cn = uv2[bn + iC];
      u_p1 = cn.x; v_p1 = cn.y;
      T_p1 = Tf[bn + iC];
      q_p1 = qf[bn + iC];
    }
  }
}

extern "C" void kernel_launch(void* const* d_in, const int* in_sizes, int n_in,
                              void* d_out, int out_size, void* d_ws, size_t ws_size,
                              hipStream_t stream) {
  const float* uv = (const float*)d_in[0];
  const float* T  = (const float*)d_in[1];
  const float* q  = (const float*)d_in[2];
  const float* ps = (const float*)d_in[3];
  float* out = (float*)d_out;
  (void)in_sizes; (void)n_in; (void)out_size; (void)d_ws; (void)ws_size;

  // host-side replay of np.linspace(1.0, 0.04, 25).astype(f32) level constants
  Tabs tb;
  const double step = (0.04 - 1.0) / 24.0;
  float bif[KLEV + 1];
  for (int i = 0; i <= KLEV; ++i)
    bif[i] = (i == KLEV) ? 0.04f : (float)(1.0 + step * (double)i);
  float bm[KLEV];
  for (int k = 0; k < KLEV; ++k) {
    bm[k] = 0.5f * (bif[k + 1] + bif[k]);
    tb.bm[k] = bm[k];
    tb.db[k] = bif[k + 1] - bif[k];
    tb.invbm[k] = 1.0f / bm[k];
  }
  tb.rlr[0] = 0.0f;
  for (int m = 1; m < KLEV; ++m) tb.rlr[m] = 287.0f * logf(bm[m - 1] / bm[m]);
  tb.dc[0] = 1.0f / (bm[1] - bm[0]);
  tb.dc[KLEV - 1] = 1.0f / (bm[KLEV - 1] - bm[KLEV - 2]);
  for (int m = 1; m < KLEV - 1; ++m) tb.dc[m] = 1.0f / (bm[m + 1] - bm[m - 1]);

  hipLaunchKernelGGL(kern_fused, dim3(NBLK), dim3(256), 0, stream,
                     uv, T, q, ps, out, tb);
}